// Round 1
// baseline (10127.756 us; speedup 1.0000x reference)
//
#include <hip/hip_runtime.h>
#include <hip/hip_bf16.h>
#include <math.h>

// ---- problem constants ----
#define Bc 4
#define Sc 1024
#define Dc 768
#define Hc 12
#define Lc 12
#define FFc 3072
#define HDc 64
#define Mtot (Bc*Sc)   // 4096 rows

typedef __bf16 bf16x8 __attribute__((ext_vector_type(8)));
typedef float f32x4 __attribute__((ext_vector_type(4)));

// =====================================================================
// Embedding: x[b,s,:] = wte[tok] + wpe[s]
// grid = B*S blocks, 256 threads
__global__ __launch_bounds__(256) void embed_kernel(const int* __restrict__ tokens,
                                                    const float* __restrict__ wte,
                                                    const float* __restrict__ wpe,
                                                    float* __restrict__ x) {
    int row = blockIdx.x;              // b*S + s
    int s = row & (Sc - 1);
    int tok = tokens[row];
    const float* wt = wte + (size_t)tok * Dc;
    const float* wp = wpe + (size_t)s * Dc;
    float* xr = x + (size_t)row * Dc;
#pragma unroll
    for (int k = 0; k < 3; ++k) {
        int d = threadIdx.x + k * 256;
        xr[d] = wt[d] + wp[d];
    }
}

// =====================================================================
// LayerNorm: out = (x-mean)*rsqrt(var+eps)*w + b ; one block per row
__global__ __launch_bounds__(256) void ln_kernel(const float* __restrict__ x,
                                                 const float* __restrict__ lw,
                                                 const float* __restrict__ lb,
                                                 float* __restrict__ out) {
    int row = blockIdx.x;
    const float* xr = x + (size_t)row * Dc;
    int t = threadIdx.x;
    float v0 = xr[t], v1 = xr[t + 256], v2 = xr[t + 512];
    float s1 = v0 + v1 + v2;
    float s2 = v0 * v0 + v1 * v1 + v2 * v2;
    __shared__ float red[8];
#pragma unroll
    for (int o = 32; o; o >>= 1) {
        s1 += __shfl_down(s1, o);
        s2 += __shfl_down(s2, o);
    }
    int wv = t >> 6;
    if ((t & 63) == 0) { red[wv] = s1; red[4 + wv] = s2; }
    __syncthreads();
    float S1 = red[0] + red[1] + red[2] + red[3];
    float S2 = red[4] + red[5] + red[6] + red[7];
    float mean = S1 * (1.0f / Dc);
    float var = S2 * (1.0f / Dc) - mean * mean;
    float rs = rsqrtf(var + 1e-5f);
    float* orow = out + (size_t)row * Dc;
    orow[t]       = (v0 - mean) * rs * lw[t]       + lb[t];
    orow[t + 256] = (v1 - mean) * rs * lw[t + 256] + lb[t + 256];
    orow[t + 512] = (v2 - mean) * rs * lw[t + 512] + lb[t + 512];
}

// =====================================================================
// bf16 MFMA GEMM: C = A[M,K] * W[K,N] (+bias) (+add) (+gelu)
// 128x128 tile, 4 waves (2x2), each wave 64x64 via 4x4 frags of 16x16x32.
// EPI: 0 = bias only, 1 = bias + addin, 2 = bias + exact gelu
template <int EPI>
__global__ __launch_bounds__(256) void gemm_kernel(const float* __restrict__ A,
                                                   const float* __restrict__ Bw,
                                                   const float* __restrict__ bias,
                                                   const float* __restrict__ addin,
                                                   float* __restrict__ Cout,
                                                   int K, int N) {
    // LDS: stride 40 bf16 (80 B, 16B-aligned rows, ~2-way bank aliasing on frag reads)
    __shared__ __bf16 As[128 * 40];
    __shared__ __bf16 Bs[128 * 40];   // transposed: Bs[col][k]
    int tid = threadIdx.x;
    int w = tid >> 6, l = tid & 63;
    int wrow = (w >> 1) * 64, wcol = (w & 1) * 64;
    int brow0 = blockIdx.x * 128;
    int bcol0 = blockIdx.y * 128;

    f32x4 acc[4][4] = {};

    int arow = tid >> 3;            // 0..31
    int acol = (tid & 7) * 4;       // 0..28
    int bkrow = tid >> 5;           // 0..7
    int bcol = (tid & 31) * 4;      // 0..124

    int k0 = (l >> 4) * 8;
    int rsel = l & 15;

    for (int kt = 0; kt < K; kt += 32) {
        // stage A tile [128][32] (row-major in LDS)
#pragma unroll
        for (int r = 0; r < 4; ++r) {
            int row = arow + r * 32;
            const float4 v = *(const float4*)(A + (size_t)(brow0 + row) * K + kt + acol);
            __bf16* dst = &As[row * 40 + acol];
            dst[0] = (__bf16)v.x; dst[1] = (__bf16)v.y;
            dst[2] = (__bf16)v.z; dst[3] = (__bf16)v.w;
        }
        // stage B tile transposed: Bs[col][k]
#pragma unroll
        for (int r = 0; r < 4; ++r) {
            int kk = bkrow + r * 8;
            const float4 v = *(const float4*)(Bw + (size_t)(kt + kk) * N + bcol0 + bcol);
            Bs[(bcol + 0) * 40 + kk] = (__bf16)v.x;
            Bs[(bcol + 1) * 40 + kk] = (__bf16)v.y;
            Bs[(bcol + 2) * 40 + kk] = (__bf16)v.z;
            Bs[(bcol + 3) * 40 + kk] = (__bf16)v.w;
        }
        __syncthreads();

        bf16x8 af[4], bfr[4];
#pragma unroll
        for (int m = 0; m < 4; ++m)
            af[m] = *(const bf16x8*)(&As[(wrow + m * 16 + rsel) * 40 + k0]);
#pragma unroll
        for (int n = 0; n < 4; ++n)
            bfr[n] = *(const bf16x8*)(&Bs[(wcol + n * 16 + rsel) * 40 + k0]);
#pragma unroll
        for (int m = 0; m < 4; ++m)
#pragma unroll
            for (int n = 0; n < 4; ++n)
                acc[m][n] = __builtin_amdgcn_mfma_f32_16x16x32_bf16(af[m], bfr[n], acc[m][n], 0, 0, 0);
        __syncthreads();
    }

    // epilogue: C[row=(l>>4)*4+i][col=l&15] per fragment (m89-verified layout)
    int r4 = (l >> 4) * 4, cc = l & 15;
#pragma unroll
    for (int m = 0; m < 4; ++m)
#pragma unroll
        for (int n = 0; n < 4; ++n) {
            int col = bcol0 + wcol + n * 16 + cc;
            float bv = bias[col];
#pragma unroll
            for (int i = 0; i < 4; ++i) {
                int row = brow0 + wrow + m * 16 + r4 + i;
                float v = acc[m][n][i] + bv;
                if (EPI == 1) v += addin[(size_t)row * N + col];
                if (EPI == 2) v = 0.5f * v * (1.0f + erff(v * 0.70710678118654752f));
                Cout[(size_t)row * N + col] = v;
            }
        }
}

// =====================================================================
// Flash-style causal attention, fp32.  grid (B*H, S/4); 4 waves, 1 q-row each.
__global__ __launch_bounds__(256) void attn_kernel(const float* __restrict__ qkv,
                                                   float* __restrict__ aout) {
    __shared__ float Kl[64 * 65];
    __shared__ float Vl[64 * 65];
    __shared__ float qs[4][64];
    __shared__ float ps[4][64];
    int bh = blockIdx.x;
    int b = bh / Hc, h = bh % Hc;
    int qt = blockIdx.y;
    int w = threadIdx.x >> 6, l = threadIdx.x & 63;
    int qrow = qt * 4 + w;
    const float* base = qkv + (size_t)b * Sc * 3 * Dc + h * HDc;

    qs[w][l] = base[(size_t)qrow * 3 * Dc + l];

    float m = -1e30f, lsum = 0.0f, acc = 0.0f;
    int ntiles = (qt * 4 + 3) / 64 + 1;

    // staging coords: 16 lanes cover one row of 64 floats (float4 each)
    int srow = threadIdx.x >> 4;          // 0..15
    int scol = (threadIdx.x & 15) * 4;    // 0..60

    for (int t = 0; t < ntiles; ++t) {
        __syncthreads();
#pragma unroll
        for (int r = 0; r < 4; ++r) {
            int j = srow + r * 16;
            const float* kp = base + (size_t)(t * 64 + j) * 3 * Dc + Dc + scol;
            const float* vp = base + (size_t)(t * 64 + j) * 3 * Dc + 2 * Dc + scol;
            float4 k4 = *(const float4*)kp;
            float4 v4 = *(const float4*)vp;
            Kl[j * 65 + scol + 0] = k4.x; Kl[j * 65 + scol + 1] = k4.y;
            Kl[j * 65 + scol + 2] = k4.z; Kl[j * 65 + scol + 3] = k4.w;
            Vl[j * 65 + scol + 0] = v4.x; Vl[j * 65 + scol + 1] = v4.y;
            Vl[j * 65 + scol + 2] = v4.z; Vl[j * 65 + scol + 3] = v4.w;
        }
        __syncthreads();

        if (t * 64 <= qrow) {
            // scores: lane l = key j in tile
            float s = 0.0f;
#pragma unroll 16
            for (int d = 0; d < 64; ++d)
                s = fmaf(qs[w][d], Kl[l * 65 + d], s);
            s *= 0.125f;                      // 1/sqrt(64)
            if (t * 64 + l > qrow) s = -1e30f;
            float tm = s;
#pragma unroll
            for (int o = 32; o; o >>= 1) tm = fmaxf(tm, __shfl_xor(tm, o));
            float mnew = fmaxf(m, tm);
            float corr = expf(m - mnew);
            float p = expf(s - mnew);
            ps[w][l] = p;
            lsum = lsum * corr + p;
            acc *= corr;
            m = mnew;
            // PV: lane l = dim d
#pragma unroll 16
            for (int j = 0; j < 64; ++j)
                acc = fmaf(ps[w][j], Vl[j * 65 + l], acc);
        }
    }
    float tot = lsum;
#pragma unroll
    for (int o = 32; o; o >>= 1) tot += __shfl_xor(tot, o);
    aout[(size_t)(b * Sc + qrow) * Dc + h * HDc + l] = acc / tot;
}

// =====================================================================
// presents copy: presents[l, kv, b, s, h, hd] = qkv[b, s, (1+kv)*D + h*HD + hd]
// pres points at layer l's region. 2*B*S*D floats, float4 per thread.
__global__ __launch_bounds__(256) void presents_kernel(const float* __restrict__ qkv,
                                                       float* __restrict__ pres) {
    size_t idx = ((size_t)blockIdx.x * 256 + threadIdx.x) * 4;
    size_t bsd = (size_t)Mtot * Dc;
    size_t kv = idx / bsd;
    size_t rem = idx - kv * bsd;
    size_t row = rem / Dc;
    size_t col = rem - row * Dc;
    float4 v = *(const float4*)(qkv + row * 3 * Dc + (1 + kv) * Dc + col);
    *(float4*)(pres + idx) = v;
}

// simple float4 copy
__global__ __launch_bounds__(256) void copy_kernel(const float* __restrict__ src,
                                                   float* __restrict__ dst) {
    size_t idx = ((size_t)blockIdx.x * 256 + threadIdx.x) * 4;
    *(float4*)(dst + idx) = *(const float4*)(src + idx);
}

// =====================================================================
extern "C" void kernel_launch(void* const* d_in, const int* in_sizes, int n_in,
                              void* d_out, int out_size, void* d_ws, size_t ws_size,
                              hipStream_t stream) {
    const int*   tokens = (const int*)d_in[0];
    const float* wte    = (const float*)d_in[1];
    const float* wpe    = (const float*)d_in[2];
    const float* ln1_w  = (const float*)d_in[3];
    const float* ln1_b  = (const float*)d_in[4];
    const float* ln2_w  = (const float*)d_in[5];
    const float* ln2_b  = (const float*)d_in[6];
    const float* W_exp  = (const float*)d_in[7];
    const float* b_exp  = (const float*)d_in[8];
    const float* W_o    = (const float*)d_in[9];
    const float* b_o    = (const float*)d_in[10];
    const float* W_ff1  = (const float*)d_in[11];
    const float* b_ff1  = (const float*)d_in[12];
    const float* W_ff2  = (const float*)d_in[13];
    const float* b_ff2  = (const float*)d_in[14];

    float* out_x    = (float*)d_out;
    float* out_pres = out_x + (size_t)Mtot * Dc;

    float* ws  = (float*)d_ws;
    float* x   = ws;                                   // M*D
    float* h   = x   + (size_t)Mtot * Dc;              // M*D (LN1 out, then attn out)
    float* add = h   + (size_t)Mtot * Dc;              // M*D (LN2 out)
    float* qkv = add + (size_t)Mtot * Dc;              // M*3D
    float* ff1 = qkv + (size_t)Mtot * 3 * Dc;          // M*FF

    embed_kernel<<<Mtot, 256, 0, stream>>>(tokens, wte, wpe, x);

    for (int lidx = 0; lidx < Lc; ++lidx) {
        // LN1
        ln_kernel<<<Mtot, 256, 0, stream>>>(x, ln1_w + lidx * Dc, ln1_b + lidx * Dc, h);
        // QKV = h @ W_exp + b_exp
        gemm_kernel<0><<<dim3(Mtot / 128, (3 * Dc) / 128), 256, 0, stream>>>(
            h, W_exp + (size_t)lidx * Dc * 3 * Dc, b_exp + (size_t)lidx * 3 * Dc,
            nullptr, qkv, Dc, 3 * Dc);
        // presents for this layer
        presents_kernel<<<(2 * (size_t)Mtot * Dc) / (256 * 4), 256, 0, stream>>>(
            qkv, out_pres + (size_t)lidx * 2 * Mtot * Dc);
        // attention -> h (reuse)
        attn_kernel<<<dim3(Bc * Hc, Sc / 4), 256, 0, stream>>>(qkv, h);
        // r = attn @ W_o + b_o + x  -> x (in place residual)
        gemm_kernel<1><<<dim3(Mtot / 128, Dc / 128), 256, 0, stream>>>(
            h, W_o + (size_t)lidx * Dc * Dc, b_o + (size_t)lidx * Dc,
            x, x, Dc, Dc);
        // LN2 -> add
        ln_kernel<<<Mtot, 256, 0, stream>>>(x, ln2_w + lidx * Dc, ln2_b + lidx * Dc, add);
        // ff1 = gelu(add @ W_ff1 + b_ff1)
        gemm_kernel<2><<<dim3(Mtot / 128, FFc / 128), 256, 0, stream>>>(
            add, W_ff1 + (size_t)lidx * Dc * FFc, b_ff1 + (size_t)lidx * FFc,
            nullptr, ff1, Dc, FFc);
        // x = ff1 @ W_ff2 + b_ff2 + add
        gemm_kernel<1><<<dim3(Mtot / 128, Dc / 128), 256, 0, stream>>>(
            ff1, W_ff2 + (size_t)lidx * FFc * Dc, b_ff2 + (size_t)lidx * Dc,
            add, x, FFc, Dc);
    }

    copy_kernel<<<((size_t)Mtot * Dc) / (256 * 4), 256, 0, stream>>>(x, out_x);
}

// Round 2
// 5562.913 us; speedup vs baseline: 1.8206x; 1.8206x over previous
//
#include <hip/hip_runtime.h>
#include <hip/hip_bf16.h>
#include <math.h>

// ---- problem constants ----
#define Bc 4
#define Sc 1024
#define Dc 768
#define Hc 12
#define Lc 12
#define FFc 3072
#define HDc 64
#define Mtot (Bc*Sc)   // 4096 rows

typedef __bf16 bf16x8 __attribute__((ext_vector_type(8)));
typedef float f32x4 __attribute__((ext_vector_type(4)));

// =====================================================================
// Embedding: x[b,s,:] = wte[tok] + wpe[s]
__global__ __launch_bounds__(256) void embed_kernel(const int* __restrict__ tokens,
                                                    const float* __restrict__ wte,
                                                    const float* __restrict__ wpe,
                                                    float* __restrict__ x) {
    int row = blockIdx.x;              // b*S + s
    int s = row & (Sc - 1);
    int tok = tokens[row];
    const float* wt = wte + (size_t)tok * Dc;
    const float* wp = wpe + (size_t)s * Dc;
    float* xr = x + (size_t)row * Dc;
#pragma unroll
    for (int k = 0; k < 3; ++k) {
        int d = threadIdx.x + k * 256;
        xr[d] = wt[d] + wp[d];
    }
}

// =====================================================================
// LayerNorm
__global__ __launch_bounds__(256) void ln_kernel(const float* __restrict__ x,
                                                 const float* __restrict__ lw,
                                                 const float* __restrict__ lb,
                                                 float* __restrict__ out) {
    int row = blockIdx.x;
    const float* xr = x + (size_t)row * Dc;
    int t = threadIdx.x;
    float v0 = xr[t], v1 = xr[t + 256], v2 = xr[t + 512];
    float s1 = v0 + v1 + v2;
    float s2 = v0 * v0 + v1 * v1 + v2 * v2;
    __shared__ float red[8];
#pragma unroll
    for (int o = 32; o; o >>= 1) {
        s1 += __shfl_down(s1, o);
        s2 += __shfl_down(s2, o);
    }
    int wv = t >> 6;
    if ((t & 63) == 0) { red[wv] = s1; red[4 + wv] = s2; }
    __syncthreads();
    float S1 = red[0] + red[1] + red[2] + red[3];
    float S2 = red[4] + red[5] + red[6] + red[7];
    float mean = S1 * (1.0f / Dc);
    float var = S2 * (1.0f / Dc) - mean * mean;
    float rs = rsqrtf(var + 1e-5f);
    float* orow = out + (size_t)row * Dc;
    orow[t]       = (v0 - mean) * rs * lw[t]       + lb[t];
    orow[t + 256] = (v1 - mean) * rs * lw[t + 256] + lb[t + 256];
    orow[t + 512] = (v2 - mean) * rs * lw[t + 512] + lb[t + 512];
}

// =====================================================================
// bf16 MFMA GEMM: C = A[M,K] * W[K,N] (+bias) (+epilogue)
// EPI: 0 = bias only, 1 = bias + addin, 2 = bias + exact gelu,
//      3 = bias + write bf16 qkv + presents (QKV gemm)
template <int EPI>
__global__ __launch_bounds__(256) void gemm_kernel(const float* __restrict__ A,
                                                   const float* __restrict__ Bw,
                                                   const float* __restrict__ bias,
                                                   const float* __restrict__ addin,
                                                   float* __restrict__ Cout,
                                                   __bf16* __restrict__ qkvb,
                                                   float* __restrict__ pres,
                                                   int K, int N) {
    __shared__ __bf16 As[128 * 40];
    __shared__ __bf16 Bs[128 * 40];   // transposed: Bs[col][k]
    int tid = threadIdx.x;
    int w = tid >> 6, l = tid & 63;
    int wrow = (w >> 1) * 64, wcol = (w & 1) * 64;
    int brow0 = blockIdx.x * 128;
    int bcol0 = blockIdx.y * 128;

    f32x4 acc[4][4] = {};

    int arow = tid >> 3;            // 0..31
    int acol = (tid & 7) * 4;       // 0..28
    int bkrow = tid >> 5;           // 0..7
    int bcol = (tid & 31) * 4;      // 0..124

    int k0 = (l >> 4) * 8;
    int rsel = l & 15;

    for (int kt = 0; kt < K; kt += 32) {
#pragma unroll
        for (int r = 0; r < 4; ++r) {
            int row = arow + r * 32;
            const float4 v = *(const float4*)(A + (size_t)(brow0 + row) * K + kt + acol);
            __bf16* dst = &As[row * 40 + acol];
            dst[0] = (__bf16)v.x; dst[1] = (__bf16)v.y;
            dst[2] = (__bf16)v.z; dst[3] = (__bf16)v.w;
        }
#pragma unroll
        for (int r = 0; r < 4; ++r) {
            int kk = bkrow + r * 8;
            const float4 v = *(const float4*)(Bw + (size_t)(kt + kk) * N + bcol0 + bcol);
            Bs[(bcol + 0) * 40 + kk] = (__bf16)v.x;
            Bs[(bcol + 1) * 40 + kk] = (__bf16)v.y;
            Bs[(bcol + 2) * 40 + kk] = (__bf16)v.z;
            Bs[(bcol + 3) * 40 + kk] = (__bf16)v.w;
        }
        __syncthreads();

        bf16x8 af[4], bfr[4];
#pragma unroll
        for (int m = 0; m < 4; ++m)
            af[m] = *(const bf16x8*)(&As[(wrow + m * 16 + rsel) * 40 + k0]);
#pragma unroll
        for (int n = 0; n < 4; ++n)
            bfr[n] = *(const bf16x8*)(&Bs[(wcol + n * 16 + rsel) * 40 + k0]);
#pragma unroll
        for (int m = 0; m < 4; ++m)
#pragma unroll
            for (int n = 0; n < 4; ++n)
                acc[m][n] = __builtin_amdgcn_mfma_f32_16x16x32_bf16(af[m], bfr[n], acc[m][n], 0, 0, 0);
        __syncthreads();
    }

    int r4 = (l >> 4) * 4, cc = l & 15;
#pragma unroll
    for (int m = 0; m < 4; ++m)
#pragma unroll
        for (int n = 0; n < 4; ++n) {
            int col = bcol0 + wcol + n * 16 + cc;
            float bv = bias[col];
#pragma unroll
            for (int i = 0; i < 4; ++i) {
                int row = brow0 + wrow + m * 16 + r4 + i;
                float v = acc[m][n][i] + bv;
                if (EPI == 1) v += addin[(size_t)row * N + col];
                if (EPI == 2) v = 0.5f * v * (1.0f + erff(v * 0.70710678118654752f));
                if (EPI == 3) {
                    qkvb[(size_t)row * 2304 + col] = (__bf16)v;
                    if (col >= 768) {
                        int kv = (col >= 1536) ? 1 : 0;
                        pres[((size_t)kv * Mtot + row) * Dc + (col - 768 - kv * 768)] = v;
                    }
                } else {
                    Cout[(size_t)row * N + col] = v;
                }
            }
        }
}

// =====================================================================
// MFMA flash attention. Block = 4 waves, 64 q-rows for one (b,h).
// grid (B*H, S/64), qt reversed for load balance.
__global__ __launch_bounds__(256) void attn_mfma_kernel(const __bf16* __restrict__ qkvb,
                                                        float* __restrict__ aout) {
    __shared__ __bf16 Ks[64 * 72];        // Ks[j][d], rows padded to 72 (144B)
    __shared__ __bf16 Vts[64 * 72];       // Vts[d][j], transposed
    __shared__ __bf16 Ps[4][16 * 72];     // per-wave P buffer [q][j]
    int bh = blockIdx.x;
    int b = bh / Hc, h = bh % Hc;
    int qt = (Sc / 64 - 1) - blockIdx.y;
    int tid = threadIdx.x;
    int w = tid >> 6, l = tid & 63;
    int lr = l & 15, lg = l >> 4;
    int qb = qt * 64;

    const __bf16* base = qkvb + (size_t)b * Sc * 2304 + h * 64;

    // Q fragments (2 k-steps over d=64) in registers
    bf16x8 qf[2];
    {
        const __bf16* qrow = base + (size_t)(qb + w * 16 + lr) * 2304 + lg * 8;
        qf[0] = *(const bf16x8*)(qrow);
        qf[1] = *(const bf16x8*)(qrow + 32);
    }

    f32x4 O[4] = {};
    float mrow[4], lrowv[4];
#pragma unroll
    for (int i = 0; i < 4; ++i) { mrow[i] = -1e30f; lrowv[i] = 0.0f; }

    int kj = tid >> 2, kc = tid & 3;            // K staging: row, 16B chunk
    int vj = tid & 63, vd0 = (tid >> 6) * 8;    // V staging: col j, d0

    for (int t = 0; t <= qt; ++t) {
        __syncthreads();
        // stage K tile: Ks[j][0..63]
#pragma unroll
        for (int it = 0; it < 2; ++it) {
            int c = kc + 4 * it;
            bf16x8 v = *(const bf16x8*)(base + (size_t)(t * 64 + kj) * 2304 + 768 + c * 8);
            *(bf16x8*)(&Ks[kj * 72 + c * 8]) = v;
        }
        // stage V transposed: Vts[d][j]
#pragma unroll
        for (int it = 0; it < 2; ++it) {
            int d0 = vd0 + 32 * it;
            bf16x8 v = *(const bf16x8*)(base + (size_t)(t * 64 + vj) * 2304 + 1536 + d0);
#pragma unroll
            for (int i = 0; i < 8; ++i)
                Vts[(d0 + i) * 72 + vj] = v[i];
        }
        __syncthreads();

        // QK^T: sc[n] = Q(16x64) . K^T(64x16-slice n)
        f32x4 sc[4] = {};
#pragma unroll
        for (int s = 0; s < 2; ++s)
#pragma unroll
            for (int n = 0; n < 4; ++n) {
                bf16x8 kf = *(const bf16x8*)(&Ks[(n * 16 + lr) * 72 + s * 32 + lg * 8]);
                sc[n] = __builtin_amdgcn_mfma_f32_16x16x32_bf16(qf[s], kf, sc[n], 0, 0, 0);
            }

        bool diag = (t == qt);
#pragma unroll
        for (int n = 0; n < 4; ++n)
#pragma unroll
            for (int i = 0; i < 4; ++i) {
                float s = sc[n][i] * 0.125f;
                if (diag) {
                    int jg = n * 16 + lr;
                    int qg = w * 16 + lg * 4 + i;
                    if (jg > qg) s = -1e30f;
                }
                sc[n][i] = s;
            }
        // online softmax over rows (row i spread across 16 lanes x 4 frags)
        float corr[4], psum[4];
#pragma unroll
        for (int i = 0; i < 4; ++i) {
            float mx = fmaxf(fmaxf(sc[0][i], sc[1][i]), fmaxf(sc[2][i], sc[3][i]));
#pragma unroll
            for (int o = 1; o < 16; o <<= 1) mx = fmaxf(mx, __shfl_xor(mx, o));
            float mnew = fmaxf(mrow[i], mx);
            corr[i] = __expf(mrow[i] - mnew);
            mrow[i] = mnew;
            psum[i] = 0.0f;
        }
#pragma unroll
        for (int n = 0; n < 4; ++n)
#pragma unroll
            for (int i = 0; i < 4; ++i) {
                float p = __expf(sc[n][i] - mrow[i]);
                psum[i] += p;
                Ps[w][(lg * 4 + i) * 72 + n * 16 + lr] = (__bf16)p;
            }
#pragma unroll
        for (int i = 0; i < 4; ++i) {
#pragma unroll
            for (int o = 1; o < 16; o <<= 1) psum[i] += __shfl_xor(psum[i], o);
            lrowv[i] = lrowv[i] * corr[i] + psum[i];
        }
#pragma unroll
        for (int n = 0; n < 4; ++n)
#pragma unroll
            for (int i = 0; i < 4; ++i) O[n][i] *= corr[i];
        // PV: O(16x64) += P(16x64) . V(64x64)
#pragma unroll
        for (int s = 0; s < 2; ++s) {
            bf16x8 pf = *(const bf16x8*)(&Ps[w][lr * 72 + s * 32 + lg * 8]);
#pragma unroll
            for (int n = 0; n < 4; ++n) {
                bf16x8 vf = *(const bf16x8*)(&Vts[(n * 16 + lr) * 72 + s * 32 + lg * 8]);
                O[n] = __builtin_amdgcn_mfma_f32_16x16x32_bf16(pf, vf, O[n], 0, 0, 0);
            }
        }
    }
    // epilogue: write fp32 attention output
    float* orow = aout + (size_t)(b * Sc + qb + w * 16 + lg * 4) * Dc + h * 64 + lr;
#pragma unroll
    for (int n = 0; n < 4; ++n)
#pragma unroll
        for (int i = 0; i < 4; ++i)
            orow[(size_t)i * Dc + n * 16] = O[n][i] / lrowv[i];
}

// simple float4 copy
__global__ __launch_bounds__(256) void copy_kernel(const float* __restrict__ src,
                                                   float* __restrict__ dst) {
    size_t idx = ((size_t)blockIdx.x * 256 + threadIdx.x) * 4;
    *(float4*)(dst + idx) = *(const float4*)(src + idx);
}

// =====================================================================
extern "C" void kernel_launch(void* const* d_in, const int* in_sizes, int n_in,
                              void* d_out, int out_size, void* d_ws, size_t ws_size,
                              hipStream_t stream) {
    const int*   tokens = (const int*)d_in[0];
    const float* wte    = (const float*)d_in[1];
    const float* wpe    = (const float*)d_in[2];
    const float* ln1_w  = (const float*)d_in[3];
    const float* ln1_b  = (const float*)d_in[4];
    const float* ln2_w  = (const float*)d_in[5];
    const float* ln2_b  = (const float*)d_in[6];
    const float* W_exp  = (const float*)d_in[7];
    const float* b_exp  = (const float*)d_in[8];
    const float* W_o    = (const float*)d_in[9];
    const float* b_o    = (const float*)d_in[10];
    const float* W_ff1  = (const float*)d_in[11];
    const float* b_ff1  = (const float*)d_in[12];
    const float* W_ff2  = (const float*)d_in[13];
    const float* b_ff2  = (const float*)d_in[14];

    float* out_x    = (float*)d_out;
    float* out_pres = out_x + (size_t)Mtot * Dc;

    float* ws  = (float*)d_ws;
    float* x    = ws;                                  // M*D f32
    float* h    = x   + (size_t)Mtot * Dc;             // M*D f32
    float* add  = h   + (size_t)Mtot * Dc;             // M*D f32
    float* ff1  = add + (size_t)Mtot * Dc;             // M*FF f32
    __bf16* qkvb = (__bf16*)(ff1 + (size_t)Mtot * FFc); // M*3D bf16

    embed_kernel<<<Mtot, 256, 0, stream>>>(tokens, wte, wpe, x);

    for (int lidx = 0; lidx < Lc; ++lidx) {
        // LN1
        ln_kernel<<<Mtot, 256, 0, stream>>>(x, ln1_w + lidx * Dc, ln1_b + lidx * Dc, h);
        // QKV = h @ W_exp + b_exp  -> bf16 qkv + fp32 presents
        gemm_kernel<3><<<dim3(Mtot / 128, (3 * Dc) / 128), 256, 0, stream>>>(
            h, W_exp + (size_t)lidx * Dc * 3 * Dc, b_exp + (size_t)lidx * 3 * Dc,
            nullptr, nullptr, qkvb, out_pres + (size_t)lidx * 2 * Mtot * Dc, Dc, 3 * Dc);
        // attention -> h
        attn_mfma_kernel<<<dim3(Bc * Hc, Sc / 64), 256, 0, stream>>>(qkvb, h);
        // x = attn @ W_o + b_o + x
        gemm_kernel<1><<<dim3(Mtot / 128, Dc / 128), 256, 0, stream>>>(
            h, W_o + (size_t)lidx * Dc * Dc, b_o + (size_t)lidx * Dc,
            x, x, nullptr, nullptr, Dc, Dc);
        // LN2 -> add
        ln_kernel<<<Mtot, 256, 0, stream>>>(x, ln2_w + lidx * Dc, ln2_b + lidx * Dc, add);
        // ff1 = gelu(add @ W_ff1 + b_ff1)
        gemm_kernel<2><<<dim3(Mtot / 128, FFc / 128), 256, 0, stream>>>(
            add, W_ff1 + (size_t)lidx * Dc * FFc, b_ff1 + (size_t)lidx * FFc,
            nullptr, ff1, nullptr, nullptr, Dc, FFc);
        // x = ff1 @ W_ff2 + b_ff2 + add
        gemm_kernel<1><<<dim3(Mtot / 128, Dc / 128), 256, 0, stream>>>(
            ff1, W_ff2 + (size_t)lidx * FFc * Dc, b_ff2 + (size_t)lidx * Dc,
            add, x, nullptr, nullptr, FFc, Dc);
    }

    copy_kernel<<<((size_t)Mtot * Dc) / (256 * 4), 256, 0, stream>>>(x, out_x);
}

// Round 3
// 2171.725 us; speedup vs baseline: 4.6635x; 2.5615x over previous
//
#include <hip/hip_runtime.h>
#include <hip/hip_bf16.h>
#include <math.h>

// ---- problem constants ----
#define Bc 4
#define Sc 1024
#define Dc 768
#define Hc 12
#define Lc 12
#define FFc 3072
#define Mtot (Bc*Sc)   // 4096 rows

typedef __bf16 bf16x8 __attribute__((ext_vector_type(8)));
typedef float f32x4 __attribute__((ext_vector_type(4)));

__device__ __forceinline__ void gload_lds16(const void* g, void* l) {
    __builtin_amdgcn_global_load_lds((const __attribute__((address_space(1))) void*)g,
                                     (__attribute__((address_space(3))) void*)l, 16, 0, 0);
}

// =====================================================================
// Embedding: x[b,s,:] = wte[tok] + wpe[s]
__global__ __launch_bounds__(256) void embed_kernel(const int* __restrict__ tokens,
                                                    const float* __restrict__ wte,
                                                    const float* __restrict__ wpe,
                                                    float* __restrict__ x) {
    int row = blockIdx.x;
    int s = row & (Sc - 1);
    int tok = tokens[row];
    const float* wt = wte + (size_t)tok * Dc;
    const float* wp = wpe + (size_t)s * Dc;
    float* xr = x + (size_t)row * Dc;
#pragma unroll
    for (int k = 0; k < 3; ++k) {
        int d = threadIdx.x + k * 256;
        xr[d] = wt[d] + wp[d];
    }
}

// =====================================================================
// Weight transpose + bf16 cast: W[K][N] f32 -> WT[N][K] bf16
__global__ __launch_bounds__(256) void transpose_kernel(const float* __restrict__ W,
                                                        __bf16* __restrict__ WT,
                                                        int K, int N) {
    __shared__ float t[32][33];
    int n0 = blockIdx.x * 32, k0 = blockIdx.y * 32;
    int tx = threadIdx.x & 31, ty = threadIdx.x >> 5;   // ty 0..7
#pragma unroll
    for (int i = 0; i < 4; ++i)
        t[ty + 8 * i][tx] = W[(size_t)(k0 + ty + 8 * i) * N + n0 + tx];
    __syncthreads();
#pragma unroll
    for (int i = 0; i < 4; ++i)
        WT[(size_t)(n0 + ty + 8 * i) * K + k0 + tx] = (__bf16)t[tx][ty + 8 * i];
}

// =====================================================================
// LayerNorm: bf16 out (+ optional fp32 out for residual use)
template <bool DUAL>
__global__ __launch_bounds__(256) void ln_kernel(const float* __restrict__ x,
                                                 const float* __restrict__ lw,
                                                 const float* __restrict__ lb,
                                                 __bf16* __restrict__ outb,
                                                 float* __restrict__ outf) {
    int row = blockIdx.x;
    const float* xr = x + (size_t)row * Dc;
    int t = threadIdx.x;
    float v0 = xr[t], v1 = xr[t + 256], v2 = xr[t + 512];
    float s1 = v0 + v1 + v2;
    float s2 = v0 * v0 + v1 * v1 + v2 * v2;
    __shared__ float red[8];
#pragma unroll
    for (int o = 32; o; o >>= 1) {
        s1 += __shfl_down(s1, o);
        s2 += __shfl_down(s2, o);
    }
    int wv = t >> 6;
    if ((t & 63) == 0) { red[wv] = s1; red[4 + wv] = s2; }
    __syncthreads();
    float S1 = red[0] + red[1] + red[2] + red[3];
    float S2 = red[4] + red[5] + red[6] + red[7];
    float mean = S1 * (1.0f / Dc);
    float var = S2 * (1.0f / Dc) - mean * mean;
    float rs = rsqrtf(var + 1e-5f);
    size_t ro = (size_t)row * Dc;
    float o0 = (v0 - mean) * rs * lw[t]       + lb[t];
    float o1 = (v1 - mean) * rs * lw[t + 256] + lb[t + 256];
    float o2 = (v2 - mean) * rs * lw[t + 512] + lb[t + 512];
    outb[ro + t]       = (__bf16)o0;
    outb[ro + t + 256] = (__bf16)o1;
    outb[ro + t + 512] = (__bf16)o2;
    if (DUAL) {
        outf[ro + t]       = o0;
        outf[ro + t + 256] = o1;
        outf[ro + t + 512] = o2;
    }
}

// =====================================================================
// bf16 MFMA GEMM, both operands row-major-K (B pre-transposed).
// BM x BM tile, 4 waves (2x2), BK=32, double-buffered global_load_lds staging,
// XOR-swizzled LDS (chunk ^= (row>>1)&3) on both write (via source) and read.
// EPI: 1 = bias + addin -> f32 ; 2 = bias + gelu -> bf16 ; 3 = QKV (bf16 + presents)
template <int BM, int EPI>
__global__ __launch_bounds__(256) void gemm_bf16(const __bf16* __restrict__ A,
                                                 const __bf16* __restrict__ BT,
                                                 const float* __restrict__ bias,
                                                 const float* __restrict__ addin,
                                                 float* __restrict__ Cf,
                                                 __bf16* __restrict__ Cb,
                                                 float* __restrict__ pres,
                                                 int K, int N) {
    constexpr int HR = BM / 32;     // frags per wave dim: 128->4, 64->2
    __shared__ __bf16 As[2][BM * 32];
    __shared__ __bf16 Bs[2][BM * 32];
    int tid = threadIdx.x;
    int w = tid >> 6, l = tid & 63;
    int wrow = (w >> 1) * (BM / 2), wcol = (w & 1) * (BM / 2);
    int brow0 = blockIdx.x * BM, bcol0 = blockIdx.y * BM;
    int rsel = l & 15, lg = l >> 4;

    f32x4 acc[HR][HR] = {};

    int srow = w * 16 + (l >> 2);   // staging local row (issue 0)
    int sslot = l & 3;

    const __bf16* Abase = A + (size_t)brow0 * K;
    const __bf16* Bbase = BT + (size_t)bcol0 * K;

    auto stage = [&](int buf, int kt) {
#pragma unroll
        for (int i = 0; i < BM / 64; ++i) {
            int row = i * 64 + srow;
            int chunk = sslot ^ ((row >> 1) & 3);
            gload_lds16(Abase + (size_t)row * K + kt + chunk * 8,
                        &As[buf][(i * 64 + w * 16) * 32]);
            gload_lds16(Bbase + (size_t)row * K + kt + chunk * 8,
                        &Bs[buf][(i * 64 + w * 16) * 32]);
        }
    };

    stage(0, 0);
    __syncthreads();
    int nk = K >> 5;
    for (int kt = 0; kt < nk; ++kt) {
        int cur = kt & 1;
        if (kt + 1 < nk) stage(cur ^ 1, (kt + 1) << 5);
        bf16x8 af[HR], bfr[HR];
#pragma unroll
        for (int m = 0; m < HR; ++m) {
            int r = wrow + m * 16 + rsel;
            af[m] = *(const bf16x8*)(&As[cur][r * 32 + (lg ^ ((r >> 1) & 3)) * 8]);
        }
#pragma unroll
        for (int n = 0; n < HR; ++n) {
            int r = wcol + n * 16 + rsel;
            bfr[n] = *(const bf16x8*)(&Bs[cur][r * 32 + (lg ^ ((r >> 1) & 3)) * 8]);
        }
#pragma unroll
        for (int m = 0; m < HR; ++m)
#pragma unroll
            for (int n = 0; n < HR; ++n)
                acc[m][n] = __builtin_amdgcn_mfma_f32_16x16x32_bf16(af[m], bfr[n], acc[m][n], 0, 0, 0);
        __syncthreads();
    }

    // epilogue: frag C[row=lg*4+i][col=rsel]
    int r4 = lg * 4, cc = rsel;
#pragma unroll
    for (int m = 0; m < HR; ++m)
#pragma unroll
        for (int n = 0; n < HR; ++n) {
            int col = bcol0 + wcol + n * 16 + cc;
            float bv = bias[col];
#pragma unroll
            for (int i = 0; i < 4; ++i) {
                int row = brow0 + wrow + m * 16 + r4 + i;
                float v = acc[m][n][i] + bv;
                if (EPI == 1) {
                    v += addin[(size_t)row * N + col];
                    Cf[(size_t)row * N + col] = v;
                }
                if (EPI == 2) {
                    v = 0.5f * v * (1.0f + erff(v * 0.70710678118654752f));
                    Cb[(size_t)row * N + col] = (__bf16)v;
                }
                if (EPI == 3) {
                    Cb[(size_t)row * N + col] = (__bf16)v;
                    if (col >= 768) {
                        int kv = (col >= 1536) ? 1 : 0;
                        pres[((size_t)kv * Mtot + row) * Dc + (col - 768 - kv * 768)] = v;
                    }
                }
            }
        }
}

// =====================================================================
// MFMA flash attention. Block = 4 waves, 64 q-rows for one (b,h). bf16 out.
__global__ __launch_bounds__(256) void attn_mfma_kernel(const __bf16* __restrict__ qkvb,
                                                        __bf16* __restrict__ aout) {
    __shared__ __bf16 Ks[64 * 72];
    __shared__ __bf16 Vts[64 * 72];
    __shared__ __bf16 Ps[4][16 * 72];
    int bh = blockIdx.x;
    int b = bh / Hc, h = bh % Hc;
    int qt = (Sc / 64 - 1) - blockIdx.y;
    int tid = threadIdx.x;
    int w = tid >> 6, l = tid & 63;
    int lr = l & 15, lg = l >> 4;
    int qb = qt * 64;

    const __bf16* base = qkvb + (size_t)b * Sc * 2304 + h * 64;

    bf16x8 qf[2];
    {
        const __bf16* qrow = base + (size_t)(qb + w * 16 + lr) * 2304 + lg * 8;
        qf[0] = *(const bf16x8*)(qrow);
        qf[1] = *(const bf16x8*)(qrow + 32);
    }

    f32x4 O[4] = {};
    float mrow[4], lrowv[4];
#pragma unroll
    for (int i = 0; i < 4; ++i) { mrow[i] = -1e30f; lrowv[i] = 0.0f; }

    int kj = tid >> 2, kc = tid & 3;
    int vj = tid & 63, vd0 = (tid >> 6) * 8;

    for (int t = 0; t <= qt; ++t) {
        __syncthreads();
#pragma unroll
        for (int it = 0; it < 2; ++it) {
            int c = kc + 4 * it;
            bf16x8 v = *(const bf16x8*)(base + (size_t)(t * 64 + kj) * 2304 + 768 + c * 8);
            *(bf16x8*)(&Ks[kj * 72 + c * 8]) = v;
        }
#pragma unroll
        for (int it = 0; it < 2; ++it) {
            int d0 = vd0 + 32 * it;
            bf16x8 v = *(const bf16x8*)(base + (size_t)(t * 64 + vj) * 2304 + 1536 + d0);
#pragma unroll
            for (int i = 0; i < 8; ++i)
                Vts[(d0 + i) * 72 + vj] = v[i];
        }
        __syncthreads();

        f32x4 sc[4] = {};
#pragma unroll
        for (int s = 0; s < 2; ++s)
#pragma unroll
            for (int n = 0; n < 4; ++n) {
                bf16x8 kf = *(const bf16x8*)(&Ks[(n * 16 + lr) * 72 + s * 32 + lg * 8]);
                sc[n] = __builtin_amdgcn_mfma_f32_16x16x32_bf16(qf[s], kf, sc[n], 0, 0, 0);
            }

        bool diag = (t == qt);
#pragma unroll
        for (int n = 0; n < 4; ++n)
#pragma unroll
            for (int i = 0; i < 4; ++i) {
                float s = sc[n][i] * 0.125f;
                if (diag) {
                    int jg = n * 16 + lr;
                    int qg = w * 16 + lg * 4 + i;
                    if (jg > qg) s = -1e30f;
                }
                sc[n][i] = s;
            }
        float corr[4], psum[4];
#pragma unroll
        for (int i = 0; i < 4; ++i) {
            float mx = fmaxf(fmaxf(sc[0][i], sc[1][i]), fmaxf(sc[2][i], sc[3][i]));
#pragma unroll
            for (int o = 1; o < 16; o <<= 1) mx = fmaxf(mx, __shfl_xor(mx, o));
            float mnew = fmaxf(mrow[i], mx);
            corr[i] = __expf(mrow[i] - mnew);
            mrow[i] = mnew;
            psum[i] = 0.0f;
        }
#pragma unroll
        for (int n = 0; n < 4; ++n)
#pragma unroll
            for (int i = 0; i < 4; ++i) {
                float p = __expf(sc[n][i] - mrow[i]);
                psum[i] += p;
                Ps[w][(lg * 4 + i) * 72 + n * 16 + lr] = (__bf16)p;
            }
#pragma unroll
        for (int i = 0; i < 4; ++i) {
#pragma unroll
            for (int o = 1; o < 16; o <<= 1) psum[i] += __shfl_xor(psum[i], o);
            lrowv[i] = lrowv[i] * corr[i] + psum[i];
        }
#pragma unroll
        for (int n = 0; n < 4; ++n)
#pragma unroll
            for (int i = 0; i < 4; ++i) O[n][i] *= corr[i];
#pragma unroll
        for (int s = 0; s < 2; ++s) {
            bf16x8 pf = *(const bf16x8*)(&Ps[w][lr * 72 + s * 32 + lg * 8]);
#pragma unroll
            for (int n = 0; n < 4; ++n) {
                bf16x8 vf = *(const bf16x8*)(&Vts[(n * 16 + lr) * 72 + s * 32 + lg * 8]);
                O[n] = __builtin_amdgcn_mfma_f32_16x16x32_bf16(pf, vf, O[n], 0, 0, 0);
            }
        }
    }
    __bf16* orow = aout + (size_t)(b * Sc + qb + w * 16 + lg * 4) * Dc + h * 64 + lr;
#pragma unroll
    for (int n = 0; n < 4; ++n)
#pragma unroll
        for (int i = 0; i < 4; ++i)
            orow[(size_t)i * Dc + n * 16] = (__bf16)(O[n][i] / lrowv[i]);
}

// simple float4 copy
__global__ __launch_bounds__(256) void copy_kernel(const float* __restrict__ src,
                                                   float* __restrict__ dst) {
    size_t idx = ((size_t)blockIdx.x * 256 + threadIdx.x) * 4;
    *(float4*)(dst + idx) = *(const float4*)(src + idx);
}

// =====================================================================
extern "C" void kernel_launch(void* const* d_in, const int* in_sizes, int n_in,
                              void* d_out, int out_size, void* d_ws, size_t ws_size,
                              hipStream_t stream) {
    const int*   tokens = (const int*)d_in[0];
    const float* wte    = (const float*)d_in[1];
    const float* wpe    = (const float*)d_in[2];
    const float* ln1_w  = (const float*)d_in[3];
    const float* ln1_b  = (const float*)d_in[4];
    const float* ln2_w  = (const float*)d_in[5];
    const float* ln2_b  = (const float*)d_in[6];
    const float* W_exp  = (const float*)d_in[7];
    const float* b_exp  = (const float*)d_in[8];
    const float* W_o    = (const float*)d_in[9];
    const float* b_o    = (const float*)d_in[10];
    const float* W_ff1  = (const float*)d_in[11];
    const float* b_ff1  = (const float*)d_in[12];
    const float* W_ff2  = (const float*)d_in[13];
    const float* b_ff2  = (const float*)d_in[14];

    float* out_x    = (float*)d_out;
    float* out_pres = out_x + (size_t)Mtot * Dc;

    float* ws   = (float*)d_ws;
    float* x    = ws;                                   // M*D f32
    float* addf = x + (size_t)Mtot * Dc;                // M*D f32 (LN2 out f32)
    __bf16* hb   = (__bf16*)(addf + (size_t)Mtot * Dc); // M*D bf16 (LN1 out / attn out)
    __bf16* addb = hb + (size_t)Mtot * Dc;              // M*D bf16 (LN2 out bf16)
    __bf16* qkvb = addb + (size_t)Mtot * Dc;            // M*3D bf16
    __bf16* ff1b = qkvb + (size_t)Mtot * 3 * Dc;        // M*FF bf16
    __bf16* wt_exp = ff1b + (size_t)Mtot * FFc;         // 2304*768
    __bf16* wt_o   = wt_exp + (size_t)2304 * 768;       // 768*768
    __bf16* wt_ff1 = wt_o   + (size_t)768 * 768;        // 3072*768
    __bf16* wt_ff2 = wt_ff1 + (size_t)3072 * 768;       // 768*3072

    embed_kernel<<<Mtot, 256, 0, stream>>>(tokens, wte, wpe, x);

    for (int lidx = 0; lidx < Lc; ++lidx) {
        // per-layer weight transposes -> bf16 W^T
        transpose_kernel<<<dim3(2304 / 32, 768 / 32), 256, 0, stream>>>(
            W_exp + (size_t)lidx * Dc * 3 * Dc, wt_exp, 768, 2304);
        transpose_kernel<<<dim3(768 / 32, 768 / 32), 256, 0, stream>>>(
            W_o + (size_t)lidx * Dc * Dc, wt_o, 768, 768);
        transpose_kernel<<<dim3(3072 / 32, 768 / 32), 256, 0, stream>>>(
            W_ff1 + (size_t)lidx * Dc * FFc, wt_ff1, 768, 3072);
        transpose_kernel<<<dim3(768 / 32, 3072 / 32), 256, 0, stream>>>(
            W_ff2 + (size_t)lidx * FFc * Dc, wt_ff2, 3072, 768);

        // LN1 -> hb (bf16)
        ln_kernel<false><<<Mtot, 256, 0, stream>>>(
            x, ln1_w + lidx * Dc, ln1_b + lidx * Dc, hb, nullptr);
        // QKV = hb @ W_exp + b_exp -> qkvb bf16 + presents f32
        gemm_bf16<128, 3><<<dim3(Mtot / 128, 2304 / 128), 256, 0, stream>>>(
            hb, wt_exp, b_exp + (size_t)lidx * 3 * Dc, nullptr, nullptr, qkvb,
            out_pres + (size_t)lidx * 2 * Mtot * Dc, 768, 2304);
        // attention -> hb (bf16)
        attn_mfma_kernel<<<dim3(Bc * Hc, Sc / 64), 256, 0, stream>>>(qkvb, hb);
        // x = hb @ W_o + b_o + x  (in place)
        gemm_bf16<64, 1><<<dim3(Mtot / 64, 768 / 64), 256, 0, stream>>>(
            hb, wt_o, b_o + (size_t)lidx * Dc, x, x, nullptr, nullptr, 768, 768);
        // LN2 -> addb (bf16) + addf (f32)
        ln_kernel<true><<<Mtot, 256, 0, stream>>>(
            x, ln2_w + lidx * Dc, ln2_b + lidx * Dc, addb, addf);
        // ff1 = gelu(addb @ W_ff1 + b_ff1) -> bf16
        gemm_bf16<128, 2><<<dim3(Mtot / 128, FFc / 128), 256, 0, stream>>>(
            addb, wt_ff1, b_ff1 + (size_t)lidx * FFc, nullptr, nullptr, ff1b, nullptr, 768, FFc);
        // x = ff1b @ W_ff2 + b_ff2 + addf
        gemm_bf16<64, 1><<<dim3(Mtot / 64, 768 / 64), 256, 0, stream>>>(
            ff1b, wt_ff2, b_ff2 + (size_t)lidx * Dc, addf, x, nullptr, nullptr, FFc, 768);
    }

    copy_kernel<<<((size_t)Mtot * Dc) / (256 * 4), 256, 0, stream>>>(x, out_x);
}